// Round 27
// baseline (118.325 us; speedup 1.0000x reference)
//
#include <hip/hip_runtime.h>
#include <hip/hip_bf16.h>

// Mamba layer, MI355X. Inputs fp32; OUTPUT fp32. Internal math fp32
// (dt/scan state fp32; B/C/u/weights in split- or single-bf16 where linear).
// Round 27: scanA stages B/C tiles as bf16 (they enter the recurrence
// linearly; dt stays fp32) -> LDS 34.3->28.9KB -> 5 blocks/CU, lb(256,5).
// Everything else identical to round 26 (114.3us).

constexpr int BSZ = 4, SEQ = 1024, DIM = 256, DIN = 512, DST = 48, DTR = 16, EPROJ = 112;
constexpr int M = BSZ * SEQ;            // 4096
constexpr int CH = 32, CL = 32;         // 32 chunks x 32 steps = 1024
constexpr int NBDS = BSZ * DIN * DST;   // 98304 scan streams x states
constexpr int NW_IN = 1024 * 256, NW_XP = EPROJ * 512, NW_OUT = 256 * 512;
constexpr int NW_TOT = NW_IN + NW_XP + NW_OUT;   // 450560
constexpr int WSPLIT_BLOCKS = (NW_TOT / 4) / 256;  // 440

using bfrag = __attribute__((ext_vector_type(8))) short;
using f32x4 = __attribute__((ext_vector_type(4))) float;
using us4   = __attribute__((ext_vector_type(4))) unsigned short;

static __device__ __forceinline__ unsigned short f2bf(float f) {
    union { float f; unsigned u; } v; v.f = f;
    unsigned r = v.u + 0x7fffu + ((v.u >> 16) & 1u);   // RTN-even
    return (unsigned short)(r >> 16);
}
static __device__ __forceinline__ float bf2f(unsigned short h) {
    union { unsigned u; float f; } v; v.u = (unsigned)h << 16;
    return v.f;
}

// ---------------- LayerNorm (blocks < M) + weight pre-split (blocks >= M) ----------------
__global__ void k_ln_wsplit(const float* __restrict__ x, const float* __restrict__ lnw,
                            const float* __restrict__ lnb,
                            unsigned short* __restrict__ xh, unsigned short* __restrict__ xl,
                            const float* __restrict__ w0, const float* __restrict__ w1,
                            const float* __restrict__ w2,
                            unsigned short* __restrict__ hi, unsigned short* __restrict__ lo) {
    int t = threadIdx.x;
    if (blockIdx.x >= M) {
        int i = (blockIdx.x - M) * 256 + t;           // float4 index
        constexpr int i0 = NW_IN >> 2, i1 = (NW_IN + NW_XP) >> 2, it = NW_TOT >> 2;
        if (i >= it) return;
        const float* src; int off;
        if (i < i0) { src = w0; off = i; }
        else if (i < i1) { src = w1; off = i - i0; }
        else { src = w2; off = i - i1; }
        float4 v = ((const float4*)src)[off];
        us4 h, l;
        h.x = f2bf(v.x); l.x = f2bf(v.x - bf2f(h.x));
        h.y = f2bf(v.y); l.y = f2bf(v.y - bf2f(h.y));
        h.z = f2bf(v.z); l.z = f2bf(v.z - bf2f(h.z));
        h.w = f2bf(v.w); l.w = f2bf(v.w - bf2f(h.w));
        ((us4*)hi)[i] = h;
        ((us4*)lo)[i] = l;
        return;
    }
    int m = blockIdx.x;
    float v = x[m * DIM + t];
    float s = v, s2 = v * v;
#pragma unroll
    for (int off = 32; off; off >>= 1) { s += __shfl_down(s, off); s2 += __shfl_down(s2, off); }
    __shared__ float ss[4], sq[4];
    int w = t >> 6;
    if ((t & 63) == 0) { ss[w] = s; sq[w] = s2; }
    __syncthreads();
    float tot = ss[0] + ss[1] + ss[2] + ss[3];
    float tq = sq[0] + sq[1] + sq[2] + sq[3];
    float mu = tot * (1.f / DIM);
    float var = tq * (1.f / DIM) - mu * mu;
    float rs = rsqrtf(var + 1e-5f);
    float o = (v - mu) * rs * lnw[t] + lnb[t];
    unsigned short h = f2bf(o);
    xh[m * DIM + t] = h;
    xl[m * DIM + t] = f2bf(o - bf2f(h));
}

// ---------------- MFMA GEMM, split-bf16; BOTH operands pre-split ----------------
template <int BM, int BN, int FM, int FN, int KSUB, int MINB>
__global__ __launch_bounds__(256, MINB) void k_gemm_mfma(
    const unsigned short* __restrict__ Ahi, const unsigned short* __restrict__ Alo,
    const unsigned short* __restrict__ Whi, const unsigned short* __restrict__ Wlo,
    float* __restrict__ outp, int lda, int Nvalid, int ldo, int Mtot) {
    constexpr int BK = 32, BKP = 40;
    __shared__ __align__(16) unsigned short Ah[BM * BKP], Al[BM * BKP];
    __shared__ __align__(16) unsigned short Bh[BN * BKP], Bl[BN * BKP];
    const int tid = threadIdx.x;
    const int lane = tid & 63;
    const int w = tid >> 6;
    const int wm = w >> 1, wn = w & 1;
    const int bm0 = blockIdx.x * BM;
    const int bn0 = blockIdx.y * BN;
    const int kb = blockIdx.z * KSUB;
    float* out = outp + (size_t)blockIdx.z * Mtot * ldo;

    f32x4 acc[FM][FN];
#pragma unroll
    for (int i = 0; i < FM; i++)
#pragma unroll
        for (int j = 0; j < FN; j++) acc[i][j] = f32x4{0.f, 0.f, 0.f, 0.f};

    for (int k0 = kb; k0 < kb + KSUB; k0 += BK) {
        for (int flat = tid * 4; flat < BM * BK; flat += 1024) {
            int r = flat >> 5, c = flat & 31;
            size_t g = (size_t)(bm0 + r) * lda + k0 + c;
            *(us4*)&Ah[r * BKP + c] = *(const us4*)(Ahi + g);
            *(us4*)&Al[r * BKP + c] = *(const us4*)(Alo + g);
        }
        for (int flat = tid * 4; flat < BN * BK; flat += 1024) {
            int r = flat >> 5, c = flat & 31;
            int gn = bn0 + r;
            us4 h = us4{0, 0, 0, 0}, l = us4{0, 0, 0, 0};
            if (gn < Nvalid) {
                h = *(const us4*)(Whi + (size_t)gn * lda + k0 + c);
                l = *(const us4*)(Wlo + (size_t)gn * lda + k0 + c);
            }
            *(us4*)&Bh[r * BKP + c] = h;
            *(us4*)&Bl[r * BKP + c] = l;
        }
        __syncthreads();

        const int kcol = (lane >> 4) * 8;
        const int rsel = lane & 15;
        bfrag afh[FM], afl[FM], bfh[FN], bfl[FN];
#pragma unroll
        for (int i = 0; i < FM; i++) {
            int row = wm * (FM * 16) + i * 16 + rsel;
            afh[i] = *(const bfrag*)&Ah[row * BKP + kcol];
            afl[i] = *(const bfrag*)&Al[row * BKP + kcol];
        }
#pragma unroll
        for (int j = 0; j < FN; j++) {
            int col = wn * (FN * 16) + j * 16 + rsel;
            bfh[j] = *(const bfrag*)&Bh[col * BKP + kcol];
            bfl[j] = *(const bfrag*)&Bl[col * BKP + kcol];
        }
#pragma unroll
        for (int i = 0; i < FM; i++)
#pragma unroll
            for (int j = 0; j < FN; j++) {
                acc[i][j] = __builtin_amdgcn_mfma_f32_16x16x32_bf16(afh[i], bfh[j], acc[i][j], 0, 0, 0);
                acc[i][j] = __builtin_amdgcn_mfma_f32_16x16x32_bf16(afh[i], bfl[j], acc[i][j], 0, 0, 0);
                acc[i][j] = __builtin_amdgcn_mfma_f32_16x16x32_bf16(afl[i], bfh[j], acc[i][j], 0, 0, 0);
            }
        __syncthreads();
    }

    const int crow = (lane >> 4) * 4;
    const int ccol = lane & 15;
#pragma unroll
    for (int i = 0; i < FM; i++)
#pragma unroll
        for (int j = 0; j < FN; j++) {
            int gn = bn0 + wn * (FN * 16) + j * 16 + ccol;
            if (gn < Nvalid) {
                int gm = bm0 + wm * (FM * 16) + i * 16 + crow;
#pragma unroll
                for (int r = 0; r < 4; r++)
                    out[(size_t)(gm + r) * ldo + gn] = acc[i][j][r];
            }
        }
}

// ---------------- causal depthwise conv(4) + bias + silu; u as bf16 hi/lo only ----------------
__global__ void k_conv(const float* __restrict__ xz, const float* __restrict__ cw,
                       const float* __restrict__ cb,
                       unsigned short* __restrict__ uh, unsigned short* __restrict__ ul) {
    int idx = blockIdx.x * 256 + threadIdx.x;
    int d4 = (idx & 127) << 2;
    int m = idx >> 7;
    int n = m & (SEQ - 1);
    const float4* xr = (const float4*)xz;
    size_t rb = (size_t)m * 256 + (idx & 127);
    float4 z4 = {0.f, 0.f, 0.f, 0.f};
    float4 x0 = xr[rb];
    float4 x1 = (n >= 1) ? xr[rb - 256] : z4;
    float4 x2 = (n >= 2) ? xr[rb - 512] : z4;
    float4 x3 = (n >= 3) ? xr[rb - 768] : z4;
    float4 wa = *(const float4*)(cw + (size_t)d4 * 4);
    float4 wb = *(const float4*)(cw + (size_t)d4 * 4 + 4);
    float4 wc = *(const float4*)(cw + (size_t)d4 * 4 + 8);
    float4 wd = *(const float4*)(cw + (size_t)d4 * 4 + 12);
    float4 cv = *(const float4*)(cb + d4);
    float4 o;
    o.x = cv.x + x0.x * wa.w + x1.x * wa.z + x2.x * wa.y + x3.x * wa.x;
    o.y = cv.y + x0.y * wb.w + x1.y * wb.z + x2.y * wb.y + x3.y * wb.x;
    o.z = cv.z + x0.z * wc.w + x1.z * wc.z + x2.z * wc.y + x3.z * wc.x;
    o.w = cv.w + x0.w * wd.w + x1.w * wd.z + x2.w * wd.y + x3.w * wd.x;
    o.x = o.x / (1.f + __expf(-o.x));
    o.y = o.y / (1.f + __expf(-o.y));
    o.z = o.z / (1.f + __expf(-o.z));
    o.w = o.w / (1.f + __expf(-o.w));
    us4 h, l;
    h.x = f2bf(o.x); l.x = f2bf(o.x - bf2f(h.x));
    h.y = f2bf(o.y); l.y = f2bf(o.y - bf2f(h.y));
    h.z = f2bf(o.z); l.z = f2bf(o.z - bf2f(h.z));
    h.w = f2bf(o.w); l.w = f2bf(o.w - bf2f(h.w));
    ((us4*)uh)[idx] = h;
    ((us4*)ul)[idx] = l;
}

// ---------------- scanA: per-chunk local scan; B/C staged bf16 -> 5 blocks/CU ----------------
__global__ __launch_bounds__(256, 5) void k_scanA(const float* __restrict__ part,
                                                  const unsigned short* __restrict__ uh,
                                                  const unsigned short* __restrict__ ul,
                                                  const float* __restrict__ dtw, const float* __restrict__ dtb,
                                                  const float* __restrict__ alog,
                                                  float* __restrict__ H, float* __restrict__ Sb,
                                                  float2* __restrict__ yT) {
    int c = blockIdx.x & (CH - 1), b = blockIdx.x >> 5;
    int t = threadIdx.x;
    int dloc = t >> 2;
    int d = blockIdx.y * 64 + dloc;
    int sq = t & 3, s0 = sq * 12;
    constexpr size_t PS = (size_t)M * EPROJ;
    float A[12];
    bool geo = true;
#pragma unroll
    for (int q = 0; q < 3; q++) {
        float4 v = ((const float4*)(alog + (size_t)d * DST + s0))[q];
        A[4 * q] = -__expf(v.x); A[4 * q + 1] = -__expf(v.y);
        A[4 * q + 2] = -__expf(v.z); A[4 * q + 3] = -__expf(v.w);
    }
#pragma unroll
    for (int s = 0; s < 12; s++) {
        float expect = (float)(s0 + s + 1);
        if (fabsf(A[s] + expect) > 1e-3f * expect) geo = false;
    }
    __shared__ __align__(16) float dts[CL][64], us[CL][64];
    __shared__ __align__(16) unsigned short Bch[CL][DST], Cch[CL][DST];
    __shared__ __align__(16) float dtr_s[CL][16], dtw_s[16][64], dtb_s[64];
    int m0 = b * SEQ + c * CL;
    for (int i = t; i < 512; i += 256) {               // u from hi/lo planes
        int nl = i >> 4, c4 = (i & 15) * 4;
        size_t g = (size_t)(m0 + nl) * DIN + blockIdx.y * 64 + c4;
        us4 h = *(const us4*)(uh + g);
        us4 l = *(const us4*)(ul + g);
        us[nl][c4 + 0] = bf2f(h.x) + bf2f(l.x);
        us[nl][c4 + 1] = bf2f(h.y) + bf2f(l.y);
        us[nl][c4 + 2] = bf2f(h.z) + bf2f(l.z);
        us[nl][c4 + 3] = bf2f(h.w) + bf2f(l.w);
    }
    if (t < 128) {
        int nl = t >> 2, c4 = (t & 3) * 4;
        size_t row = (size_t)(m0 + nl) * EPROJ + c4;
        float4 a = *(const float4*)(part + row);
        float4 b2 = *(const float4*)(part + PS + row);
        *(float4*)&dtr_s[nl][c4] = make_float4(a.x + b2.x, a.y + b2.y, a.z + b2.z, a.w + b2.w);
    }
    for (int i = t; i < 768; i += 256) {               // B and C -> bf16 (linear operands)
        int half = i & 1, j = i >> 1;
        int nl = j / 12, c4 = (j % 12) * 4;
        size_t row = (size_t)(m0 + nl) * EPROJ + DTR + half * DST + c4;
        float4 a = *(const float4*)(part + row);
        float4 b2 = *(const float4*)(part + PS + row);
        us4 s;
        s.x = f2bf(a.x + b2.x); s.y = f2bf(a.y + b2.y);
        s.z = f2bf(a.z + b2.z); s.w = f2bf(a.w + b2.w);
        if (half == 0) *(us4*)&Bch[nl][c4] = s;
        else           *(us4*)&Cch[nl][c4] = s;
    }
    {
        int dl = t >> 2, qg = (t & 3) * 4;
        float4 v = *(const float4*)(dtw + (size_t)(blockIdx.y * 64 + dl) * DTR + qg);
        dtw_s[qg + 0][dl] = v.x; dtw_s[qg + 1][dl] = v.y;
        dtw_s[qg + 2][dl] = v.z; dtw_s[qg + 3][dl] = v.w;
    }
    if (t < 64) dtb_s[t] = dtb[blockIdx.y * 64 + t];
    __syncthreads();
    for (int i = t; i < CL * 64; i += 256) {
        int nl = i >> 6, dl = i & 63;
        float acc = dtb_s[dl];
#pragma unroll
        for (int q = 0; q < DTR; q++) acc = fmaf(dtr_s[nl][q], dtw_s[q][dl], acc);
        dts[nl][dl] = (acc > 20.f) ? acc : log1pf(__expf(acc));
    }
    __syncthreads();
    float h0 = 0.f, h1 = 0.f, h2 = 0.f, h3 = 0.f, h4 = 0.f, h5 = 0.f,
          h6 = 0.f, h7 = 0.f, h8 = 0.f, h9 = 0.f, h10 = 0.f, h11 = 0.f, S = 0.f;
    const unsigned short* BcF = &Bch[0][0];
    const unsigned short* CcF = &Cch[0][0];
    int ro = s0;
    float A0 = A[0];
#pragma unroll 4
    for (int nl = 0; nl < CL; nl++) {
        float dtv = dts[nl][dloc];
        float uv = us[nl][dloc];
        us4 b0 = *(const us4*)(BcF + ro);
        us4 b1 = *(const us4*)(BcF + ro + 4);
        us4 b2 = *(const us4*)(BcF + ro + 8);
        us4 c0 = *(const us4*)(CcF + ro);
        us4 c1 = *(const us4*)(CcF + ro + 4);
        us4 c2 = *(const us4*)(CcF + ro + 8);
        ro += DST;
        float dtu = dtv * uv;
        S += dtv;
        if (geo) {
            float r = __expf(-dtv);
            float dA0 = __expf(dtv * A0);
            float r2 = r * r, r4 = r2 * r2;
            float dA1 = dA0 * r,  dA2 = dA0 * r2, dA3 = dA1 * r2;
            float dA4 = dA0 * r4, dA5 = dA1 * r4, dA6 = dA2 * r4, dA7 = dA3 * r4;
            float dA8 = dA4 * r4, dA9 = dA5 * r4, dA10 = dA6 * r4, dA11 = dA7 * r4;
            h0 = fmaf(dA0, h0, dtu * bf2f(b0.x));  h1 = fmaf(dA1, h1, dtu * bf2f(b0.y));
            h2 = fmaf(dA2, h2, dtu * bf2f(b0.z));  h3 = fmaf(dA3, h3, dtu * bf2f(b0.w));
            h4 = fmaf(dA4, h4, dtu * bf2f(b1.x));  h5 = fmaf(dA5, h5, dtu * bf2f(b1.y));
            h6 = fmaf(dA6, h6, dtu * bf2f(b1.z));  h7 = fmaf(dA7, h7, dtu * bf2f(b1.w));
            h8 = fmaf(dA8, h8, dtu * bf2f(b2.x));  h9 = fmaf(dA9, h9, dtu * bf2f(b2.y));
            h10 = fmaf(dA10, h10, dtu * bf2f(b2.z)); h11 = fmaf(dA11, h11, dtu * bf2f(b2.w));
        } else {
            h0 = fmaf(__expf(dtv * A[0]), h0, dtu * bf2f(b0.x));
            h1 = fmaf(__expf(dtv * A[1]), h1, dtu * bf2f(b0.y));
            h2 = fmaf(__expf(dtv * A[2]), h2, dtu * bf2f(b0.z));
            h3 = fmaf(__expf(dtv * A[3]), h3, dtu * bf2f(b0.w));
            h4 = fmaf(__expf(dtv * A[4]), h4, dtu * bf2f(b1.x));
            h5 = fmaf(__expf(dtv * A[5]), h5, dtu * bf2f(b1.y));
            h6 = fmaf(__expf(dtv * A[6]), h6, dtu * bf2f(b1.z));
            h7 = fmaf(__expf(dtv * A[7]), h7, dtu * bf2f(b1.w));
            h8 = fmaf(__expf(dtv * A[8]), h8, dtu * bf2f(b2.x));
            h9 = fmaf(__expf(dtv * A[9]), h9, dtu * bf2f(b2.y));
            h10 = fmaf(__expf(dtv * A[10]), h10, dtu * bf2f(b2.z));
            h11 = fmaf(__expf(dtv * A[11]), h11, dtu * bf2f(b2.w));
        }
        float y0 = h0 * bf2f(c0.x);
        y0 = fmaf(h1, bf2f(c0.y), y0);
        y0 = fmaf(h2, bf2f(c0.z), y0);
        float y1 = h3 * bf2f(c0.w);
        y1 = fmaf(h4, bf2f(c1.x), y1);
        y1 = fmaf(h5, bf2f(c1.y), y1);
        float y2 = h6 * bf2f(c1.z);
        y2 = fmaf(h7, bf2f(c1.w), y2);
        y2 = fmaf(h8, bf2f(c2.x), y2);
        float y3 = h9 * bf2f(c2.y);
        y3 = fmaf(h10, bf2f(c2.z), y3);
        y3 = fmaf(h11, bf2f(c2.w), y3);
        float y = (y0 + y1) + (y2 + y3);
        y += __shfl_xor(y, 1);
        y += __shfl_xor(y, 2);
        if (sq == 0)
            yT[(size_t)(m0 + nl) * DIN + d] = make_float2(y, S);
    }
    size_t hb = (size_t)c * NBDS + ((size_t)(b * DIN + d)) * DST + s0;
    ((float4*)(H + hb))[0] = make_float4(h0, h1, h2, h3);
    ((float4*)(H + hb))[1] = make_float4(h4, h5, h6, h7);
    ((float4*)(H + hb))[2] = make_float4(h8, h9, h10, h11);
    if (sq == 0) Sb[c * (BSZ * DIN) + b * DIN + d] = S;
}

// ---------------- scanB: carry scan over chunks; carry[c] = state BEFORE chunk c ----------------
__global__ void k_scanB(const float* __restrict__ H, const float* __restrict__ Sb,
                        const float* __restrict__ alog, float* __restrict__ carry) {
    int idx = blockIdx.x * 256 + threadIdx.x;   // [0, NBDS)
    int s = idx % DST;
    int bd = idx / DST;
    float A = -__expf(alog[(size_t)(bd & (DIN - 1)) * DST + s]);
    float car = 0.f;
    for (int c = 0; c < CH; c++) {
        size_t o = (size_t)c * NBDS + idx;
        float h = H[o];
        float sc = Sb[c * (BSZ * DIN) + bd];
        carry[o] = car;
        car = fmaf(__expf(A * sc), car, h);
    }
}

// ---------------- scanC: parallel patch; yc emitted as bf16 hi/lo planes ----------------
__global__ __launch_bounds__(256, 4) void k_scanC(
    const float* __restrict__ part,
    const unsigned short* __restrict__ uh, const unsigned short* __restrict__ ul,
    const float* __restrict__ xz, const float* __restrict__ Dw,
    const float* __restrict__ alog, const float* __restrict__ carry,
    const float2* __restrict__ yT,
    unsigned short* __restrict__ ych, unsigned short* __restrict__ ycl) {
    int c = blockIdx.x & (CH - 1), b = blockIdx.x >> 5;
    int t = threadIdx.x;
    int d = blockIdx.y * 64 + (t & 63);
    int msub = t >> 6;
    int m0 = b * SEQ + c * CL;
    constexpr size_t PS = (size_t)M * EPROJ;
    __shared__ __align__(16) float Cls[CL][DST];
    for (int i = t; i < 384; i += 256) {
        int r = i / 12, c4 = (i % 12) * 4;
        size_t row = (size_t)(m0 + r) * EPROJ + DTR + DST + c4;
        float4 a = *(const float4*)(part + row);
        float4 b2 = *(const float4*)(part + PS + row);
        *(float4*)&Cls[r][c4] = make_float4(a.x + b2.x, a.y + b2.y, a.z + b2.z, a.w + b2.w);
    }
    float cr[48];
    {
        const float4* cp = (const float4*)(carry + (size_t)c * NBDS + ((size_t)(b * DIN + d)) * DST);
#pragma unroll
        for (int q = 0; q < 12; q++) {
            float4 v = cp[q];
            cr[4 * q] = v.x; cr[4 * q + 1] = v.y; cr[4 * q + 2] = v.z; cr[4 * q + 3] = v.w;
        }
    }
    bool geo = true;
    {
        const float4* ap = (const float4*)(alog + (size_t)d * DST);
#pragma unroll
        for (int q = 0; q < 12; q++) {
            float4 v = ap[q];
            float e0 = (float)(4 * q + 1), e1 = (float)(4 * q + 2),
                  e2 = (float)(4 * q + 3), e3 = (float)(4 * q + 4);
            if (fabsf(__expf(v.x) - e0) > 1e-3f * e0) geo = false;
            if (fabsf(__expf(v.y) - e1) > 1e-3f * e1) geo = false;
            if (fabsf(__expf(v.z) - e2) > 1e-3f * e2) geo = false;
            if (fabsf(__expf(v.w) - e3) > 1e-3f * e3) geo = false;
        }
    }
    float Dv = Dw[d];
    __syncthreads();
#pragma unroll
    for (int i = 0; i < 8; i++) {
        int mrow = msub + 4 * i;
        size_t m = (size_t)(m0 + mrow);
        float2 yt = yT[m * DIN + d];
        float uv = bf2f(uh[m * DIN + d]) + bf2f(ul[m * DIN + d]);
        float zv = xz[m * (2 * DIN) + DIN + d];
        float corr;
        const float4* Crow = (const float4*)&Cls[mrow][0];
        if (geo) {
            float rho = __expf(-yt.y);
            float r2 = rho * rho, r4 = r2 * r2;
            float p0 = rho, p1 = r2, p2 = r2 * rho, p3 = r4;
            float a0 = 0.f, a1 = 0.f, a2 = 0.f, a3 = 0.f;
#pragma unroll
            for (int k = 0; k < 12; k++) {
                float4 C4 = Crow[k];
                a0 = fmaf(C4.x * cr[4 * k + 0], p0, a0); p0 *= r4;
                a1 = fmaf(C4.y * cr[4 * k + 1], p1, a1); p1 *= r4;
                a2 = fmaf(C4.z * cr[4 * k + 2], p2, a2); p2 *= r4;
                a3 = fmaf(C4.w * cr[4 * k + 3], p3, a3); p3 *= r4;
            }
            corr = (a0 + a1) + (a2 + a3);
        } else {
            corr = 0.f;
            const float* ar = alog + (size_t)d * DST;
#pragma unroll
            for (int s = 0; s < 48; s++) {
                float Av = -__expf(ar[s]);
                corr = fmaf(Cls[mrow][s] * cr[s], __expf(Av * yt.y), corr);
            }
        }
        float yv = fmaf(uv, Dv, yt.x + corr);
        float sz = zv / (1.f + __expf(-zv));
        float o = yv * sz;
        unsigned short hh = f2bf(o);
        ych[m * DIN + d] = hh;
        ycl[m * DIN + d] = f2bf(o - bf2f(hh));
    }
}

extern "C" void kernel_launch(void* const* d_in, const int* in_sizes, int n_in,
                              void* d_out, int out_size, void* d_ws, size_t ws_size,
                              hipStream_t stream) {
    const float* x     = (const float*)d_in[0];
    const float* lnw   = (const float*)d_in[1];
    const float* lnb   = (const float*)d_in[2];
    const float* w_in  = (const float*)d_in[3];   // (1024, 256)
    const float* cw    = (const float*)d_in[4];   // (512, 4)
    const float* cb    = (const float*)d_in[5];
    const float* w_xp  = (const float*)d_in[6];   // (112, 512)
    const float* dtw   = (const float*)d_in[7];   // (512, 16)
    const float* dtb   = (const float*)d_in[8];
    const float* alog  = (const float*)d_in[9];   // (512, 48)
    const float* Dw    = (const float*)d_in[10];
    const float* w_out = (const float*)d_in[11];  // (256, 512)

    float* ws = (float*)d_ws;
    float* xz      = ws;                               // 4,194,304
    float* xp_part = xz + (size_t)M * 2 * DIN;         // 2 x M x EPROJ = 917,504
    float* H       = xp_part + 2 * (size_t)M * EPROJ;  // 3,145,728
    float* Sb      = H + (size_t)CH * NBDS;            //    65,536
    float* carry   = Sb + CH * BSZ * DIN;              // 3,145,728
    float* yT      = carry + (size_t)CH * NBDS;        // 8,388,608 (M*DIN float2)
    unsigned short* xnh = (unsigned short*)(yT + 2 * (size_t)M * DIN);  // M*DIM
    unsigned short* xnl = xnh + (size_t)M * DIM;
    unsigned short* uh  = xnl + (size_t)M * DIM;       // M*DIN
    unsigned short* ul  = uh + (size_t)M * DIN;
    unsigned short* ych = ul + (size_t)M * DIN;        // M*DIN
    unsigned short* ycl = ych + (size_t)M * DIN;
    unsigned short* whi = ycl + (size_t)M * DIN;       // NW_TOT
    unsigned short* wlo = whi + NW_TOT;
    size_t need = (size_t)((char*)(wlo + NW_TOT) - (char*)ws);   // ~95 MB
    if (ws_size < need) return;              // fail visibly (zeros) if ws too small

    const unsigned short* whi_in  = whi;
    const unsigned short* wlo_in  = wlo;
    const unsigned short* whi_xp  = whi + NW_IN;
    const unsigned short* wlo_xp  = wlo + NW_IN;
    const unsigned short* whi_out = whi + NW_IN + NW_XP;
    const unsigned short* wlo_out = wlo + NW_IN + NW_XP;

    k_ln_wsplit<<<M + WSPLIT_BLOCKS, 256, 0, stream>>>(x, lnw, lnb, xnh, xnl,
                                                       w_in, w_xp, w_out, whi, wlo);
    // in_proj: 64x64 tiles -> grid (64,16) = 1024 blocks (4/CU)
    k_gemm_mfma<64, 64, 2, 2, 256, 4><<<dim3(M / 64, 1024 / 64, 1), 256, 0, stream>>>(
        xnh, xnl, whi_in, wlo_in, xz, 256, 1024, 1024, M);
    k_conv<<<(M * DIN / 4) / 256, 256, 0, stream>>>(xz, cw, cb, uh, ul);
    // x_proj: 32x32 tiles, split-K=2 -> grid (128, 4, 2) = 1024 blocks (4/CU)
    k_gemm_mfma<32, 32, 1, 1, 256, 4><<<dim3(M / 32, 4, 2), 256, 0, stream>>>(
        uh, ul, whi_xp, wlo_xp, xp_part, 512, EPROJ, EPROJ, M);
    k_scanA<<<dim3(BSZ * CH, 8), 256, 0, stream>>>(xp_part, uh, ul, dtw, dtb, alog, H, Sb, (float2*)yT);
    k_scanB<<<NBDS / 256, 256, 0, stream>>>(H, Sb, alog, carry);
    k_scanC<<<dim3(BSZ * CH, 8), 256, 0, stream>>>(xp_part, uh, ul, xz, Dw, alog, carry,
                                                   (const float2*)yT, ych, ycl);
    // out_proj: 32x32 tiles, no split-K -> grid (128, 8) = 1024 blocks (4/CU)
    k_gemm_mfma<32, 32, 1, 1, 512, 4><<<dim3(M / 32, 8, 1), 256, 0, stream>>>(
        ych, ycl, whi_out, wlo_out, (float*)d_out, 512, 256, 256, M);
}

// Round 28
// 114.251 us; speedup vs baseline: 1.0357x; 1.0357x over previous
//
#include <hip/hip_runtime.h>
#include <hip/hip_bf16.h>

// Mamba layer, MI355X. Inputs fp32; OUTPUT fp32. Internal math fp32.
// Round 28 (FINAL): revert to round-26 best configuration (114.3us, absmax
// 0.0078). r27's bf16 B/C staging regressed (+4us, 2x absmax) and is dropped.
// Pipeline: ln+wsplit -> in_proj(MFMA split-bf16) -> conv -> x_proj ->
// scanA (local chunk scan) -> scanB (carry) -> scanC (parallel patch) -> out_proj.

constexpr int BSZ = 4, SEQ = 1024, DIM = 256, DIN = 512, DST = 48, DTR = 16, EPROJ = 112;
constexpr int M = BSZ * SEQ;            // 4096
constexpr int CH = 32, CL = 32;         // 32 chunks x 32 steps = 1024
constexpr int NBDS = BSZ * DIN * DST;   // 98304 scan streams x states
constexpr int NW_IN = 1024 * 256, NW_XP = EPROJ * 512, NW_OUT = 256 * 512;
constexpr int NW_TOT = NW_IN + NW_XP + NW_OUT;   // 450560
constexpr int WSPLIT_BLOCKS = (NW_TOT / 4) / 256;  // 440

using bfrag = __attribute__((ext_vector_type(8))) short;
using f32x4 = __attribute__((ext_vector_type(4))) float;
using us4   = __attribute__((ext_vector_type(4))) unsigned short;

static __device__ __forceinline__ unsigned short f2bf(float f) {
    union { float f; unsigned u; } v; v.f = f;
    unsigned r = v.u + 0x7fffu + ((v.u >> 16) & 1u);   // RTN-even
    return (unsigned short)(r >> 16);
}
static __device__ __forceinline__ float bf2f(unsigned short h) {
    union { unsigned u; float f; } v; v.u = (unsigned)h << 16;
    return v.f;
}

// ---------------- LayerNorm (blocks < M) + weight pre-split (blocks >= M) ----------------
__global__ void k_ln_wsplit(const float* __restrict__ x, const float* __restrict__ lnw,
                            const float* __restrict__ lnb,
                            unsigned short* __restrict__ xh, unsigned short* __restrict__ xl,
                            const float* __restrict__ w0, const float* __restrict__ w1,
                            const float* __restrict__ w2,
                            unsigned short* __restrict__ hi, unsigned short* __restrict__ lo) {
    int t = threadIdx.x;
    if (blockIdx.x >= M) {
        int i = (blockIdx.x - M) * 256 + t;           // float4 index
        constexpr int i0 = NW_IN >> 2, i1 = (NW_IN + NW_XP) >> 2, it = NW_TOT >> 2;
        if (i >= it) return;
        const float* src; int off;
        if (i < i0) { src = w0; off = i; }
        else if (i < i1) { src = w1; off = i - i0; }
        else { src = w2; off = i - i1; }
        float4 v = ((const float4*)src)[off];
        us4 h, l;
        h.x = f2bf(v.x); l.x = f2bf(v.x - bf2f(h.x));
        h.y = f2bf(v.y); l.y = f2bf(v.y - bf2f(h.y));
        h.z = f2bf(v.z); l.z = f2bf(v.z - bf2f(h.z));
        h.w = f2bf(v.w); l.w = f2bf(v.w - bf2f(h.w));
        ((us4*)hi)[i] = h;
        ((us4*)lo)[i] = l;
        return;
    }
    int m = blockIdx.x;
    float v = x[m * DIM + t];
    float s = v, s2 = v * v;
#pragma unroll
    for (int off = 32; off; off >>= 1) { s += __shfl_down(s, off); s2 += __shfl_down(s2, off); }
    __shared__ float ss[4], sq[4];
    int w = t >> 6;
    if ((t & 63) == 0) { ss[w] = s; sq[w] = s2; }
    __syncthreads();
    float tot = ss[0] + ss[1] + ss[2] + ss[3];
    float tq = sq[0] + sq[1] + sq[2] + sq[3];
    float mu = tot * (1.f / DIM);
    float var = tq * (1.f / DIM) - mu * mu;
    float rs = rsqrtf(var + 1e-5f);
    float o = (v - mu) * rs * lnw[t] + lnb[t];
    unsigned short h = f2bf(o);
    xh[m * DIM + t] = h;
    xl[m * DIM + t] = f2bf(o - bf2f(h));
}

// ---------------- MFMA GEMM, split-bf16; BOTH operands pre-split ----------------
template <int BM, int BN, int FM, int FN, int KSUB, int MINB>
__global__ __launch_bounds__(256, MINB) void k_gemm_mfma(
    const unsigned short* __restrict__ Ahi, const unsigned short* __restrict__ Alo,
    const unsigned short* __restrict__ Whi, const unsigned short* __restrict__ Wlo,
    float* __restrict__ outp, int lda, int Nvalid, int ldo, int Mtot) {
    constexpr int BK = 32, BKP = 40;
    __shared__ __align__(16) unsigned short Ah[BM * BKP], Al[BM * BKP];
    __shared__ __align__(16) unsigned short Bh[BN * BKP], Bl[BN * BKP];
    const int tid = threadIdx.x;
    const int lane = tid & 63;
    const int w = tid >> 6;
    const int wm = w >> 1, wn = w & 1;
    const int bm0 = blockIdx.x * BM;
    const int bn0 = blockIdx.y * BN;
    const int kb = blockIdx.z * KSUB;
    float* out = outp + (size_t)blockIdx.z * Mtot * ldo;

    f32x4 acc[FM][FN];
#pragma unroll
    for (int i = 0; i < FM; i++)
#pragma unroll
        for (int j = 0; j < FN; j++) acc[i][j] = f32x4{0.f, 0.f, 0.f, 0.f};

    for (int k0 = kb; k0 < kb + KSUB; k0 += BK) {
        for (int flat = tid * 4; flat < BM * BK; flat += 1024) {
            int r = flat >> 5, c = flat & 31;
            size_t g = (size_t)(bm0 + r) * lda + k0 + c;
            *(us4*)&Ah[r * BKP + c] = *(const us4*)(Ahi + g);
            *(us4*)&Al[r * BKP + c] = *(const us4*)(Alo + g);
        }
        for (int flat = tid * 4; flat < BN * BK; flat += 1024) {
            int r = flat >> 5, c = flat & 31;
            int gn = bn0 + r;
            us4 h = us4{0, 0, 0, 0}, l = us4{0, 0, 0, 0};
            if (gn < Nvalid) {
                h = *(const us4*)(Whi + (size_t)gn * lda + k0 + c);
                l = *(const us4*)(Wlo + (size_t)gn * lda + k0 + c);
            }
            *(us4*)&Bh[r * BKP + c] = h;
            *(us4*)&Bl[r * BKP + c] = l;
        }
        __syncthreads();

        const int kcol = (lane >> 4) * 8;
        const int rsel = lane & 15;
        bfrag afh[FM], afl[FM], bfh[FN], bfl[FN];
#pragma unroll
        for (int i = 0; i < FM; i++) {
            int row = wm * (FM * 16) + i * 16 + rsel;
            afh[i] = *(const bfrag*)&Ah[row * BKP + kcol];
            afl[i] = *(const bfrag*)&Al[row * BKP + kcol];
        }
#pragma unroll
        for (int j = 0; j < FN; j++) {
            int col = wn * (FN * 16) + j * 16 + rsel;
            bfh[j] = *(const bfrag*)&Bh[col * BKP + kcol];
            bfl[j] = *(const bfrag*)&Bl[col * BKP + kcol];
        }
#pragma unroll
        for (int i = 0; i < FM; i++)
#pragma unroll
            for (int j = 0; j < FN; j++) {
                acc[i][j] = __builtin_amdgcn_mfma_f32_16x16x32_bf16(afh[i], bfh[j], acc[i][j], 0, 0, 0);
                acc[i][j] = __builtin_amdgcn_mfma_f32_16x16x32_bf16(afh[i], bfl[j], acc[i][j], 0, 0, 0);
                acc[i][j] = __builtin_amdgcn_mfma_f32_16x16x32_bf16(afl[i], bfh[j], acc[i][j], 0, 0, 0);
            }
        __syncthreads();
    }

    const int crow = (lane >> 4) * 4;
    const int ccol = lane & 15;
#pragma unroll
    for (int i = 0; i < FM; i++)
#pragma unroll
        for (int j = 0; j < FN; j++) {
            int gn = bn0 + wn * (FN * 16) + j * 16 + ccol;
            if (gn < Nvalid) {
                int gm = bm0 + wm * (FM * 16) + i * 16 + crow;
#pragma unroll
                for (int r = 0; r < 4; r++)
                    out[(size_t)(gm + r) * ldo + gn] = acc[i][j][r];
            }
        }
}

// ---------------- causal depthwise conv(4) + bias + silu; u as bf16 hi/lo only ----------------
__global__ void k_conv(const float* __restrict__ xz, const float* __restrict__ cw,
                       const float* __restrict__ cb,
                       unsigned short* __restrict__ uh, unsigned short* __restrict__ ul) {
    int idx = blockIdx.x * 256 + threadIdx.x;
    int d4 = (idx & 127) << 2;
    int m = idx >> 7;
    int n = m & (SEQ - 1);
    const float4* xr = (const float4*)xz;
    size_t rb = (size_t)m * 256 + (idx & 127);
    float4 z4 = {0.f, 0.f, 0.f, 0.f};
    float4 x0 = xr[rb];
    float4 x1 = (n >= 1) ? xr[rb - 256] : z4;
    float4 x2 = (n >= 2) ? xr[rb - 512] : z4;
    float4 x3 = (n >= 3) ? xr[rb - 768] : z4;
    float4 wa = *(const float4*)(cw + (size_t)d4 * 4);
    float4 wb = *(const float4*)(cw + (size_t)d4 * 4 + 4);
    float4 wc = *(const float4*)(cw + (size_t)d4 * 4 + 8);
    float4 wd = *(const float4*)(cw + (size_t)d4 * 4 + 12);
    float4 cv = *(const float4*)(cb + d4);
    float4 o;
    o.x = cv.x + x0.x * wa.w + x1.x * wa.z + x2.x * wa.y + x3.x * wa.x;
    o.y = cv.y + x0.y * wb.w + x1.y * wb.z + x2.y * wb.y + x3.y * wb.x;
    o.z = cv.z + x0.z * wc.w + x1.z * wc.z + x2.z * wc.y + x3.z * wc.x;
    o.w = cv.w + x0.w * wd.w + x1.w * wd.z + x2.w * wd.y + x3.w * wd.x;
    o.x = o.x / (1.f + __expf(-o.x));
    o.y = o.y / (1.f + __expf(-o.y));
    o.z = o.z / (1.f + __expf(-o.z));
    o.w = o.w / (1.f + __expf(-o.w));
    us4 h, l;
    h.x = f2bf(o.x); l.x = f2bf(o.x - bf2f(h.x));
    h.y = f2bf(o.y); l.y = f2bf(o.y - bf2f(h.y));
    h.z = f2bf(o.z); l.z = f2bf(o.z - bf2f(h.z));
    h.w = f2bf(o.w); l.w = f2bf(o.w - bf2f(h.w));
    ((us4*)uh)[idx] = h;
    ((us4*)ul)[idx] = l;
}

// ---------------- scanA: per-chunk local scan -> yT(float2), H_end, S ----------------
__global__ __launch_bounds__(256, 4) void k_scanA(const float* __restrict__ part,
                                                  const unsigned short* __restrict__ uh,
                                                  const unsigned short* __restrict__ ul,
                                                  const float* __restrict__ dtw, const float* __restrict__ dtb,
                                                  const float* __restrict__ alog,
                                                  float* __restrict__ H, float* __restrict__ Sb,
                                                  float2* __restrict__ yT) {
    int c = blockIdx.x & (CH - 1), b = blockIdx.x >> 5;
    int t = threadIdx.x;
    int dloc = t >> 2;
    int d = blockIdx.y * 64 + dloc;
    int sq = t & 3, s0 = sq * 12;
    constexpr size_t PS = (size_t)M * EPROJ;
    float A[12];
    bool geo = true;
#pragma unroll
    for (int q = 0; q < 3; q++) {
        float4 v = ((const float4*)(alog + (size_t)d * DST + s0))[q];
        A[4 * q] = -__expf(v.x); A[4 * q + 1] = -__expf(v.y);
        A[4 * q + 2] = -__expf(v.z); A[4 * q + 3] = -__expf(v.w);
    }
#pragma unroll
    for (int s = 0; s < 12; s++) {
        float expect = (float)(s0 + s + 1);
        if (fabsf(A[s] + expect) > 1e-3f * expect) geo = false;
    }
    __shared__ __align__(16) float dts[CL][64], us[CL][64], Bc[CL][DST], Cc[CL][DST];
    __shared__ __align__(16) float dtr_s[CL][16], dtw_s[16][64], dtb_s[64];
    int m0 = b * SEQ + c * CL;
    for (int i = t; i < 512; i += 256) {               // u from hi/lo planes
        int nl = i >> 4, c4 = (i & 15) * 4;
        size_t g = (size_t)(m0 + nl) * DIN + blockIdx.y * 64 + c4;
        us4 h = *(const us4*)(uh + g);
        us4 l = *(const us4*)(ul + g);
        us[nl][c4 + 0] = bf2f(h.x) + bf2f(l.x);
        us[nl][c4 + 1] = bf2f(h.y) + bf2f(l.y);
        us[nl][c4 + 2] = bf2f(h.z) + bf2f(l.z);
        us[nl][c4 + 3] = bf2f(h.w) + bf2f(l.w);
    }
    if (t < 128) {
        int nl = t >> 2, c4 = (t & 3) * 4;
        size_t row = (size_t)(m0 + nl) * EPROJ + c4;
        float4 a = *(const float4*)(part + row);
        float4 b2 = *(const float4*)(part + PS + row);
        *(float4*)&dtr_s[nl][c4] = make_float4(a.x + b2.x, a.y + b2.y, a.z + b2.z, a.w + b2.w);
    }
    for (int i = t; i < 768; i += 256) {               // B and C (2 partials)
        int half = i & 1, j = i >> 1;
        int nl = j / 12, c4 = (j % 12) * 4;
        size_t row = (size_t)(m0 + nl) * EPROJ + DTR + half * DST + c4;
        float4 a = *(const float4*)(part + row);
        float4 b2 = *(const float4*)(part + PS + row);
        float4 s = make_float4(a.x + b2.x, a.y + b2.y, a.z + b2.z, a.w + b2.w);
        if (half == 0) *(float4*)&Bc[nl][c4] = s;
        else           *(float4*)&Cc[nl][c4] = s;
    }
    {
        int dl = t >> 2, qg = (t & 3) * 4;
        float4 v = *(const float4*)(dtw + (size_t)(blockIdx.y * 64 + dl) * DTR + qg);
        dtw_s[qg + 0][dl] = v.x; dtw_s[qg + 1][dl] = v.y;
        dtw_s[qg + 2][dl] = v.z; dtw_s[qg + 3][dl] = v.w;
    }
    if (t < 64) dtb_s[t] = dtb[blockIdx.y * 64 + t];
    __syncthreads();
    for (int i = t; i < CL * 64; i += 256) {
        int nl = i >> 6, dl = i & 63;
        float acc = dtb_s[dl];
#pragma unroll
        for (int q = 0; q < DTR; q++) acc = fmaf(dtr_s[nl][q], dtw_s[q][dl], acc);
        dts[nl][dl] = (acc > 20.f) ? acc : log1pf(__expf(acc));
    }
    __syncthreads();
    float h0 = 0.f, h1 = 0.f, h2 = 0.f, h3 = 0.f, h4 = 0.f, h5 = 0.f,
          h6 = 0.f, h7 = 0.f, h8 = 0.f, h9 = 0.f, h10 = 0.f, h11 = 0.f, S = 0.f;
    const float* BcF = &Bc[0][0];
    const float* CcF = &Cc[0][0];
    int ro = s0;
    float A0 = A[0];
#pragma unroll 4
    for (int nl = 0; nl < CL; nl++) {
        float dtv = dts[nl][dloc];
        float uv = us[nl][dloc];
        float4 B0 = *(const float4*)(BcF + ro);
        float4 B1 = *(const float4*)(BcF + ro + 4);
        float4 B2 = *(const float4*)(BcF + ro + 8);
        float4 C0 = *(const float4*)(CcF + ro);
        float4 C1 = *(const float4*)(CcF + ro + 4);
        float4 C2 = *(const float4*)(CcF + ro + 8);
        ro += DST;
        float dtu = dtv * uv;
        S += dtv;
        if (geo) {
            float r = __expf(-dtv);
            float dA0 = __expf(dtv * A0);
            float r2 = r * r, r4 = r2 * r2;
            float dA1 = dA0 * r,  dA2 = dA0 * r2, dA3 = dA1 * r2;
            float dA4 = dA0 * r4, dA5 = dA1 * r4, dA6 = dA2 * r4, dA7 = dA3 * r4;
            float dA8 = dA4 * r4, dA9 = dA5 * r4, dA10 = dA6 * r4, dA11 = dA7 * r4;
            h0 = fmaf(dA0, h0, dtu * B0.x);  h1 = fmaf(dA1, h1, dtu * B0.y);
            h2 = fmaf(dA2, h2, dtu * B0.z);  h3 = fmaf(dA3, h3, dtu * B0.w);
            h4 = fmaf(dA4, h4, dtu * B1.x);  h5 = fmaf(dA5, h5, dtu * B1.y);
            h6 = fmaf(dA6, h6, dtu * B1.z);  h7 = fmaf(dA7, h7, dtu * B1.w);
            h8 = fmaf(dA8, h8, dtu * B2.x);  h9 = fmaf(dA9, h9, dtu * B2.y);
            h10 = fmaf(dA10, h10, dtu * B2.z); h11 = fmaf(dA11, h11, dtu * B2.w);
        } else {
            h0 = fmaf(__expf(dtv * A[0]), h0, dtu * B0.x);
            h1 = fmaf(__expf(dtv * A[1]), h1, dtu * B0.y);
            h2 = fmaf(__expf(dtv * A[2]), h2, dtu * B0.z);
            h3 = fmaf(__expf(dtv * A[3]), h3, dtu * B0.w);
            h4 = fmaf(__expf(dtv * A[4]), h4, dtu * B1.x);
            h5 = fmaf(__expf(dtv * A[5]), h5, dtu * B1.y);
            h6 = fmaf(__expf(dtv * A[6]), h6, dtu * B1.z);
            h7 = fmaf(__expf(dtv * A[7]), h7, dtu * B1.w);
            h8 = fmaf(__expf(dtv * A[8]), h8, dtu * B2.x);
            h9 = fmaf(__expf(dtv * A[9]), h9, dtu * B2.y);
            h10 = fmaf(__expf(dtv * A[10]), h10, dtu * B2.z);
            h11 = fmaf(__expf(dtv * A[11]), h11, dtu * B2.w);
        }
        float y0 = h0 * C0.x;
        y0 = fmaf(h1, C0.y, y0);
        y0 = fmaf(h2, C0.z, y0);
        float y1 = h3 * C0.w;
        y1 = fmaf(h4, C1.x, y1);
        y1 = fmaf(h5, C1.y, y1);
        float y2 = h6 * C1.z;
        y2 = fmaf(h7, C1.w, y2);
        y2 = fmaf(h8, C2.x, y2);
        float y3 = h9 * C2.y;
        y3 = fmaf(h10, C2.z, y3);
        y3 = fmaf(h11, C2.w, y3);
        float y = (y0 + y1) + (y2 + y3);
        y += __shfl_xor(y, 1);
        y += __shfl_xor(y, 2);
        if (sq == 0)
            yT[(size_t)(m0 + nl) * DIN + d] = make_float2(y, S);
    }
    size_t hb = (size_t)c * NBDS + ((size_t)(b * DIN + d)) * DST + s0;
    ((float4*)(H + hb))[0] = make_float4(h0, h1, h2, h3);
    ((float4*)(H + hb))[1] = make_float4(h4, h5, h6, h7);
    ((float4*)(H + hb))[2] = make_float4(h8, h9, h10, h11);
    if (sq == 0) Sb[c * (BSZ * DIN) + b * DIN + d] = S;
}

// ---------------- scanB: carry scan over chunks; carry[c] = state BEFORE chunk c ----------------
__global__ void k_scanB(const float* __restrict__ H, const float* __restrict__ Sb,
                        const float* __restrict__ alog, float* __restrict__ carry) {
    int idx = blockIdx.x * 256 + threadIdx.x;   // [0, NBDS)
    int s = idx % DST;
    int bd = idx / DST;
    float A = -__expf(alog[(size_t)(bd & (DIN - 1)) * DST + s]);
    float car = 0.f;
    for (int c = 0; c < CH; c++) {
        size_t o = (size_t)c * NBDS + idx;
        float h = H[o];
        float sc = Sb[c * (BSZ * DIN) + bd];
        carry[o] = car;
        car = fmaf(__expf(A * sc), car, h);
    }
}

// ---------------- scanC: parallel patch; yc emitted as bf16 hi/lo planes ----------------
__global__ __launch_bounds__(256, 4) void k_scanC(
    const float* __restrict__ part,
    const unsigned short* __restrict__ uh, const unsigned short* __restrict__ ul,
    const float* __restrict__ xz, const float* __restrict__ Dw,
    const float* __restrict__ alog, const float* __restrict__ carry,
    const float2* __restrict__ yT,
    unsigned short* __restrict__ ych, unsigned short* __restrict__ ycl) {
    int c = blockIdx.x & (CH - 1), b = blockIdx.x >> 5;
    int t = threadIdx.x;
    int d = blockIdx.y * 64 + (t & 63);
    int msub = t >> 6;
    int m0 = b * SEQ + c * CL;
    constexpr size_t PS = (size_t)M * EPROJ;
    __shared__ __align__(16) float Cls[CL][DST];
    for (int i = t; i < 384; i += 256) {
        int r = i / 12, c4 = (i % 12) * 4;
        size_t row = (size_t)(m0 + r) * EPROJ + DTR + DST + c4;
        float4 a = *(const float4*)(part + row);
        float4 b2 = *(const float4*)(part + PS + row);
        *(float4*)&Cls[r][c4] = make_float4(a.x + b2.x, a.y + b2.y, a.z + b2.z, a.w + b2.w);
    }
    float cr[48];
    {
        const float4* cp = (const float4*)(carry + (size_t)c * NBDS + ((size_t)(b * DIN + d)) * DST);
#pragma unroll
        for (int q = 0; q < 12; q++) {
            float4 v = cp[q];
            cr[4 * q] = v.x; cr[4 * q + 1] = v.y; cr[4 * q + 2] = v.z; cr[4 * q + 3] = v.w;
        }
    }
    bool geo = true;
    {
        const float4* ap = (const float4*)(alog + (size_t)d * DST);
#pragma unroll
        for (int q = 0; q < 12; q++) {
            float4 v = ap[q];
            float e0 = (float)(4 * q + 1), e1 = (float)(4 * q + 2),
                  e2 = (float)(4 * q + 3), e3 = (float)(4 * q + 4);
            if (fabsf(__expf(v.x) - e0) > 1e-3f * e0) geo = false;
            if (fabsf(__expf(v.y) - e1) > 1e-3f * e1) geo = false;
            if (fabsf(__expf(v.z) - e2) > 1e-3f * e2) geo = false;
            if (fabsf(__expf(v.w) - e3) > 1e-3f * e3) geo = false;
        }
    }
    float Dv = Dw[d];
    __syncthreads();
#pragma unroll
    for (int i = 0; i < 8; i++) {
        int mrow = msub + 4 * i;
        size_t m = (size_t)(m0 + mrow);
        float2 yt = yT[m * DIN + d];
        float uv = bf2f(uh[m * DIN + d]) + bf2f(ul[m * DIN + d]);
        float zv = xz[m * (2 * DIN) + DIN + d];
        float corr;
        const float4* Crow = (const float4*)&Cls[mrow][0];
        if (geo) {
            float rho = __expf(-yt.y);
            float r2 = rho * rho, r4 = r2 * r2;
            float p0 = rho, p1 = r2, p2 = r2 * rho, p3 = r4;
            float a0 = 0.f, a1 = 0.f, a2 = 0.f, a3 = 0.f;
#pragma unroll
            for (int k = 0; k < 12; k++) {
                float4 C4 = Crow[k];
                a0 = fmaf(C4.x * cr[4 * k + 0], p0, a0); p0 *= r4;
                a1 = fmaf(C4.y * cr[4 * k + 1], p1, a1); p1 *= r4;
                a2 = fmaf(C4.z * cr[4 * k + 2], p2, a2); p2 *= r4;
                a3 = fmaf(C4.w * cr[4 * k + 3], p3, a3); p3 *= r4;
            }
            corr = (a0 + a1) + (a2 + a3);
        } else {
            corr = 0.f;
            const float* ar = alog + (size_t)d * DST;
#pragma unroll
            for (int s = 0; s < 48; s++) {
                float Av = -__expf(ar[s]);
                corr = fmaf(Cls[mrow][s] * cr[s], __expf(Av * yt.y), corr);
            }
        }
        float yv = fmaf(uv, Dv, yt.x + corr);
        float sz = zv / (1.f + __expf(-zv));
        float o = yv * sz;
        unsigned short hh = f2bf(o);
        ych[m * DIN + d] = hh;
        ycl[m * DIN + d] = f2bf(o - bf2f(hh));
    }
}

extern "C" void kernel_launch(void* const* d_in, const int* in_sizes, int n_in,
                              void* d_out, int out_size, void* d_ws, size_t ws_size,
                              hipStream_t stream) {
    const float* x     = (const float*)d_in[0];
    const float* lnw   = (const float*)d_in[1];
    const float* lnb   = (const float*)d_in[2];
    const float* w_in  = (const float*)d_in[3];   // (1024, 256)
    const float* cw    = (const float*)d_in[4];   // (512, 4)
    const float* cb    = (const float*)d_in[5];
    const float* w_xp  = (const float*)d_in[6];   // (112, 512)
    const float* dtw   = (const float*)d_in[7];   // (512, 16)
    const float* dtb   = (const float*)d_in[8];
    const float* alog  = (const float*)d_in[9];   // (512, 48)
    const float* Dw    = (const float*)d_in[10];
    const float* w_out = (const float*)d_in[11];  // (256, 512)

    float* ws = (float*)d_ws;
    float* xz      = ws;                               // 4,194,304
    float* xp_part = xz + (size_t)M * 2 * DIN;         // 2 x M x EPROJ = 917,504
    float* H       = xp_part + 2 * (size_t)M * EPROJ;  // 3,145,728
    float* Sb      = H + (size_t)CH * NBDS;            //    65,536
    float* carry   = Sb + CH * BSZ * DIN;              // 3,145,728
    float* yT      = carry + (size_t)CH * NBDS;        // 8,388,608 (M*DIN float2)
    unsigned short* xnh = (unsigned short*)(yT + 2 * (size_t)M * DIN);  // M*DIM
    unsigned short* xnl = xnh + (size_t)M * DIM;
    unsigned short* uh  = xnl + (size_t)M * DIM;       // M*DIN
    unsigned short* ul  = uh + (size_t)M * DIN;
    unsigned short* ych = ul + (size_t)M * DIN;        // M*DIN
    unsigned short* ycl = ych + (size_t)M * DIN;
    unsigned short* whi = ycl + (size_t)M * DIN;       // NW_TOT
    unsigned short* wlo = whi + NW_TOT;
    size_t need = (size_t)((char*)(wlo + NW_TOT) - (char*)ws);   // ~95 MB
    if (ws_size < need) return;              // fail visibly (zeros) if ws too small

    const unsigned short* whi_in  = whi;
    const unsigned short* wlo_in  = wlo;
    const unsigned short* whi_xp  = whi + NW_IN;
    const unsigned short* wlo_xp  = wlo + NW_IN;
    const unsigned short* whi_out = whi + NW_IN + NW_XP;
    const unsigned short* wlo_out = wlo + NW_IN + NW_XP;

    k_ln_wsplit<<<M + WSPLIT_BLOCKS, 256, 0, stream>>>(x, lnw, lnb, xnh, xnl,
                                                       w_in, w_xp, w_out, whi, wlo);
    // in_proj: 64x64 tiles -> grid (64,16) = 1024 blocks (4/CU)
    k_gemm_mfma<64, 64, 2, 2, 256, 4><<<dim3(M / 64, 1024 / 64, 1), 256, 0, stream>>>(
        xnh, xnl, whi_in, wlo_in, xz, 256, 1024, 1024, M);
    k_conv<<<(M * DIN / 4) / 256, 256, 0, stream>>>(xz, cw, cb, uh, ul);
    // x_proj: 32x32 tiles, split-K=2 -> grid (128, 4, 2) = 1024 blocks (4/CU)
    k_gemm_mfma<32, 32, 1, 1, 256, 4><<<dim3(M / 32, 4, 2), 256, 0, stream>>>(
        uh, ul, whi_xp, wlo_xp, xp_part, 512, EPROJ, EPROJ, M);
    k_scanA<<<dim3(BSZ * CH, 8), 256, 0, stream>>>(xp_part, uh, ul, dtw, dtb, alog, H, Sb, (float2*)yT);
    k_scanB<<<NBDS / 256, 256, 0, stream>>>(H, Sb, alog, carry);
    k_scanC<<<dim3(BSZ * CH, 8), 256, 0, stream>>>(xp_part, uh, ul, xz, Dw, alog, carry,
                                                   (const float2*)yT, ych, ycl);
    // out_proj: 32x32 tiles, no split-K -> grid (128, 8) = 1024 blocks (4/CU)
    k_gemm_mfma<32, 32, 1, 1, 512, 4><<<dim3(M / 32, 8, 1), 256, 0, stream>>>(
        ych, ycl, whi_out, wlo_out, (float*)d_out, 512, 256, 256, M);
}